// Round 1
// baseline (322.347 us; speedup 1.0000x reference)
//
#include <hip/hip_runtime.h>

#define BB 2
#define NN 4096
#define CIN 128
#define CC 64

typedef __attribute__((ext_vector_type(4))) float floatx4;
typedef __attribute__((ext_vector_type(8))) short short8;

__device__ __forceinline__ short f2bf(float f) {
    unsigned u = __float_as_uint(f);
    u += 0x7fffu + ((u >> 16) & 1u);   // RNE
    return (short)(u >> 16);
}

__device__ __forceinline__ float sigf(float x) {
    return 1.0f / (1.0f + __expf(-x));
}

// ---------------------------------------------------------------------------
// Kernel A: h = relu(relu(x@W1+b1)@W2+b2); u = h.wa_u; v = h.wa_v;
// store hT[b][c][n] as bf16 (transposed for MFMA B-fragment vector loads)
// 32 rows per block, 256 threads. LDS ~75KB -> 2 blocks/CU.
// ---------------------------------------------------------------------------
__global__ __launch_bounds__(256) void feat_kernel(
    const float* __restrict__ x, const float* __restrict__ W1,
    const float* __restrict__ b1, const float* __restrict__ W2,
    const float* __restrict__ b2, const float* __restrict__ Wa,
    short* __restrict__ hT, float* __restrict__ u, float* __restrict__ v)
{
    __shared__ float W1s[CIN * CC];      // 32KB
    __shared__ float W2s[CC * CC];       // 16KB
    __shared__ float xs[32 * 132];       // padded stride 132 -> conflict-free
    __shared__ float h1s[32 * 68];       // padded stride 68

    const int t = threadIdx.x;
    const int row0 = blockIdx.x * 32;    // global row in [0, B*N)

    {   // stage W1, W2, x tile (float4, coalesced)
        const floatx4* s1 = (const floatx4*)W1;
        floatx4* d1 = (floatx4*)W1s;
        for (int i = t; i < CIN * CC / 4; i += 256) d1[i] = s1[i];
        const floatx4* s2 = (const floatx4*)W2;
        floatx4* d2 = (floatx4*)W2s;
        for (int i = t; i < CC * CC / 4; i += 256) d2[i] = s2[i];
        const floatx4* sx = (const floatx4*)(x + (size_t)row0 * CIN);
        for (int i = t; i < 32 * CIN / 4; i += 256) {
            int rw = i >> 5, c4 = i & 31;
            *(floatx4*)(xs + rw * 132 + c4 * 4) = sx[i];
        }
    }
    __syncthreads();

    const int n  = t >> 3;       // 0..31 local row
    const int cg = t & 7;
    const int c0 = cg * 8;

    float acc[8];
#pragma unroll
    for (int i = 0; i < 8; i++) acc[i] = b1[c0 + i];
    for (int k = 0; k < CIN; k++) {
        float a = xs[n * 132 + k];
        const float* w = &W1s[k * CC + c0];
#pragma unroll
        for (int i = 0; i < 8; i++) acc[i] = fmaf(a, w[i], acc[i]);
    }
#pragma unroll
    for (int i = 0; i < 8; i++) h1s[n * 68 + c0 + i] = fmaxf(acc[i], 0.0f);
    __syncthreads();

    float acc2[8];
#pragma unroll
    for (int i = 0; i < 8; i++) acc2[i] = b2[c0 + i];
    for (int k = 0; k < CC; k++) {
        float a = h1s[n * 68 + k];
        const float* w = &W2s[k * CC + c0];
#pragma unroll
        for (int i = 0; i < 8; i++) acc2[i] = fmaf(a, w[i], acc2[i]);
    }
#pragma unroll
    for (int i = 0; i < 8; i++) acc2[i] = fmaxf(acc2[i], 0.0f);

    // u, v: partial dot per thread, reduce across the 8 threads of this row
    float pu = 0.0f, pv = 0.0f;
#pragma unroll
    for (int i = 0; i < 8; i++) {
        pu = fmaf(acc2[i], Wa[c0 + i], pu);
        pv = fmaf(acc2[i], Wa[CC + c0 + i], pv);
    }
    pu += __shfl_down(pu, 4, 8); pv += __shfl_down(pv, 4, 8);
    pu += __shfl_down(pu, 2, 8); pv += __shfl_down(pv, 2, 8);
    pu += __shfl_down(pu, 1, 8); pv += __shfl_down(pv, 1, 8);

    const int grow = row0 + n;           // global row
    if (cg == 0) { u[grow] = pu; v[grow] = pv; }

    const int b  = grow >> 12;
    const int nn = grow & (NN - 1);
#pragma unroll
    for (int i = 0; i < 8; i++)
        hT[((size_t)(b * CC + c0 + i)) * NN + nn] = f2bf(acc2[i]);
}

// ---------------------------------------------------------------------------
// Kernel B: r[row] = sum_j sigmoid(u[row] + v[j] + ba) * adj[row][j]
// one block per row, float4 coalesced.
// ---------------------------------------------------------------------------
__global__ __launch_bounds__(256) void rowsum_kernel(
    const float* __restrict__ adj, const float* __restrict__ u,
    const float* __restrict__ v, const float* __restrict__ ba,
    float* __restrict__ r)
{
    const int row = blockIdx.x;          // 0..B*N-1
    const int b = row >> 12;
    const int t = threadIdx.x;
    const float un = u[row] + ba[0];
    const floatx4* arow = (const floatx4*)(adj + (size_t)row * NN);
    const floatx4* vb = (const floatx4*)(v + b * NN);

    float p = 0.0f;
#pragma unroll
    for (int i = 0; i < 4; i++) {
        int idx = t + i * 256;
        floatx4 a4 = arow[idx];
        floatx4 v4 = vb[idx];
        p += a4.x * sigf(un + v4.x);
        p += a4.y * sigf(un + v4.y);
        p += a4.z * sigf(un + v4.z);
        p += a4.w * sigf(un + v4.w);
    }
#pragma unroll
    for (int off = 32; off > 0; off >>= 1) p += __shfl_down(p, off);

    __shared__ float red[4];
    if ((t & 63) == 0) red[t >> 6] = p;
    __syncthreads();
    if (t == 0) r[row] = red[0] + red[1] + red[2] + red[3];
}

// ---------------------------------------------------------------------------
// Kernel C: a[row][j] = sigmoid(u+v+ba)*adj/r  (write fp32) and
//           h_out = a @ h  via mfma_f32_16x16x32_bf16, j split 4-way/wave,
//           partials combined with atomicAdd into zeroed h_out.
// adj loaded directly in A-fragment layout (lane=row&15, quad -> 8 consec j):
// per row the 4 quads x 2 float4 cover a full 128B line -> full-line HBM eff.
// ---------------------------------------------------------------------------
__global__ __launch_bounds__(256) void attn_kernel(
    const float* __restrict__ adj, const float* __restrict__ u,
    const float* __restrict__ v, const float* __restrict__ ba,
    const float* __restrict__ r, const short* __restrict__ hT,
    float* __restrict__ hout, float* __restrict__ aout)
{
    const int wave = threadIdx.x >> 6;   // 0..3 -> j quarter
    const int lane = threadIdx.x & 63;
    const int quad = lane >> 4;
    const int m16  = lane & 15;

    const int tile = blockIdx.x;         // 0..511, 16 rows each
    const int row0 = tile * 16;
    const int b  = row0 >> 12;
    const int n0 = row0 & (NN - 1);
    const int n  = n0 + m16;             // this lane's A-row

    const size_t rowbase = ((size_t)(b * NN + n)) * NN;
    const float un    = u[b * NN + n] + ba[0];
    const float inv_r = 1.0f / (r[b * NN + n] + 1e-10f);
    const float* vb = v + b * NN;

    floatx4 acc[4];
#pragma unroll
    for (int g = 0; g < 4; g++) acc[g] = (floatx4){0.f, 0.f, 0.f, 0.f};

    const int j0base = wave * 1024;
#pragma unroll 2
    for (int step = 0; step < 32; step++) {
        const int jb = j0base + step * 32 + quad * 8;
        const float* ap = adj + rowbase + jb;
        floatx4 a0 = *(const floatx4*)ap;
        floatx4 a1 = *(const floatx4*)(ap + 4);
        floatx4 v0 = *(const floatx4*)(vb + jb);
        floatx4 v1 = *(const floatx4*)(vb + jb + 4);

        float av[8] = {a0.x, a0.y, a0.z, a0.w, a1.x, a1.y, a1.z, a1.w};
        float vv[8] = {v0.x, v0.y, v0.z, v0.w, v1.x, v1.y, v1.z, v1.w};

        floatx4 o0, o1;
        short8 af;
#pragma unroll
        for (int i = 0; i < 8; i++) {
            float s = av[i] * sigf(un + vv[i]) * inv_r;
            if (i < 4) o0[i] = s; else o1[i - 4] = s;
            af[i] = f2bf(s);
        }
        *(floatx4*)(aout + rowbase + jb)     = o0;
        *(floatx4*)(aout + rowbase + jb + 4) = o1;

#pragma unroll
        for (int g = 0; g < 4; g++) {
            const short8* bp = (const short8*)(hT + ((size_t)(b * CC + g * 16 + m16)) * NN + jb);
            acc[g] = __builtin_amdgcn_mfma_f32_16x16x32_bf16(af, *bp, acc[g], 0, 0, 0);
        }
    }

    // C/D layout: col = lane&15 (channel), row = quad*4 + reg
#pragma unroll
    for (int g = 0; g < 4; g++) {
        const int c = g * 16 + m16;
#pragma unroll
        for (int i = 0; i < 4; i++) {
            const int nr = n0 + quad * 4 + i;
            atomicAdd(&hout[((size_t)(b * NN + nr)) * CC + c], acc[g][i]);
        }
    }
}

// ---------------------------------------------------------------------------
extern "C" void kernel_launch(void* const* d_in, const int* in_sizes, int n_in,
                              void* d_out, int out_size, void* d_ws, size_t ws_size,
                              hipStream_t stream) {
    (void)in_sizes; (void)n_in; (void)out_size; (void)ws_size;
    const float* x   = (const float*)d_in[0];
    const float* adj = (const float*)d_in[1];
    const float* W1  = (const float*)d_in[2];
    const float* b1  = (const float*)d_in[3];
    const float* W2  = (const float*)d_in[4];
    const float* b2  = (const float*)d_in[5];
    const float* Wa  = (const float*)d_in[6];
    const float* ba  = (const float*)d_in[7];

    float* hout = (float*)d_out;                       // [B,N,64]
    float* aout = hout + (size_t)BB * NN * CC;         // [B,N,N]

    char* ws = (char*)d_ws;
    short* hT = (short*)ws;                            // bf16 [B][64][N] : 1MB
    float* u  = (float*)(ws + (size_t)BB * CC * NN * sizeof(short));
    float* vv = u + BB * NN;
    float* r  = vv + BB * NN;

    hipMemsetAsync(d_out, 0, (size_t)BB * NN * CC * sizeof(float), stream);
    feat_kernel<<<BB * NN / 32, 256, 0, stream>>>(x, W1, b1, W2, b2, Wa, hT, u, vv);
    rowsum_kernel<<<BB * NN, 256, 0, stream>>>(adj, u, vv, ba, r);
    attn_kernel<<<BB * NN / 16, 256, 0, stream>>>(adj, u, vv, ba, r, hT, hout, aout);
}

// Round 2
// 315.652 us; speedup vs baseline: 1.0212x; 1.0212x over previous
//
#include <hip/hip_runtime.h>

#define BB 2
#define NN 4096
#define CIN 128
#define CC 64

typedef __attribute__((ext_vector_type(4))) float floatx4;
typedef __attribute__((ext_vector_type(8))) short short8;

__device__ __forceinline__ short f2bf(float f) {
    unsigned u = __float_as_uint(f);
    u += 0x7fffu + ((u >> 16) & 1u);   // RNE
    return (short)(u >> 16);
}

// sigmoid via v_exp_f32 + v_rcp_f32 (avoid precise-division expansion)
__device__ __forceinline__ float sigf(float x) {
    return __builtin_amdgcn_rcpf(1.0f + __expf(-x));
}

// ---------------------------------------------------------------------------
// feat_v2: h = relu(relu(x@W1+b1)@W2+b2); u,v scalars; hT bf16 transposed.
// 16 rows/block, 256 threads (16 rows x 16 cgroups x 4 ch), grid 512.
// LDS ~61KB -> 2 blocks/CU -> 8 waves/CU.
// ---------------------------------------------------------------------------
__global__ __launch_bounds__(256) void feat_v2(
    const float* __restrict__ x, const float* __restrict__ W1,
    const float* __restrict__ b1, const float* __restrict__ W2,
    const float* __restrict__ b2, const float* __restrict__ Wa,
    const float* __restrict__ ba,
    short* __restrict__ hT, float* __restrict__ u, float* __restrict__ v)
{
    __shared__ float W1s[CIN * CC];      // 32KB
    __shared__ float W2s[CC * CC];       // 16KB
    __shared__ float xs[16 * 132];       // 8.4KB padded
    __shared__ float h1s[16 * 68];       // 4.4KB padded

    const int t = threadIdx.x;
    const int row0 = blockIdx.x * 16;

    {
        const floatx4* s1 = (const floatx4*)W1;
        floatx4* d1 = (floatx4*)W1s;
        for (int i = t; i < CIN * CC / 4; i += 256) d1[i] = s1[i];
        const floatx4* s2 = (const floatx4*)W2;
        floatx4* d2 = (floatx4*)W2s;
        for (int i = t; i < CC * CC / 4; i += 256) d2[i] = s2[i];
        const floatx4* sx = (const floatx4*)(x + (size_t)row0 * CIN);
        for (int i = t; i < 16 * CIN / 4; i += 256) {
            int rw = i >> 5, c4 = i & 31;
            *(floatx4*)(xs + rw * 132 + c4 * 4) = sx[i];
        }
    }
    __syncthreads();

    const int n  = t >> 4;       // 0..15 local row
    const int cg = t & 15;
    const int c0 = cg * 4;

    float acc[4];
#pragma unroll
    for (int i = 0; i < 4; i++) acc[i] = b1[c0 + i];
    for (int k = 0; k < CIN; k++) {
        float a = xs[n * 132 + k];
        const floatx4 w = *(const floatx4*)&W1s[k * CC + c0];
#pragma unroll
        for (int i = 0; i < 4; i++) acc[i] = fmaf(a, w[i], acc[i]);
    }
#pragma unroll
    for (int i = 0; i < 4; i++) h1s[n * 68 + c0 + i] = fmaxf(acc[i], 0.0f);
    __syncthreads();

    float acc2[4];
#pragma unroll
    for (int i = 0; i < 4; i++) acc2[i] = b2[c0 + i];
    for (int k = 0; k < CC; k++) {
        float a = h1s[n * 68 + k];
        const floatx4 w = *(const floatx4*)&W2s[k * CC + c0];
#pragma unroll
        for (int i = 0; i < 4; i++) acc2[i] = fmaf(a, w[i], acc2[i]);
    }
#pragma unroll
    for (int i = 0; i < 4; i++) acc2[i] = fmaxf(acc2[i], 0.0f);

    float pu = 0.0f, pv = 0.0f;
#pragma unroll
    for (int i = 0; i < 4; i++) {
        pu = fmaf(acc2[i], Wa[c0 + i], pu);
        pv = fmaf(acc2[i], Wa[CC + c0 + i], pv);
    }
    pu += __shfl_down(pu, 8, 16); pv += __shfl_down(pv, 8, 16);
    pu += __shfl_down(pu, 4, 16); pv += __shfl_down(pv, 4, 16);
    pu += __shfl_down(pu, 2, 16); pv += __shfl_down(pv, 2, 16);
    pu += __shfl_down(pu, 1, 16); pv += __shfl_down(pv, 1, 16);

    const int grow = row0 + n;
    if (cg == 0) { u[grow] = pu + ba[0]; v[grow] = pv; }

    const int b  = grow >> 12;
    const int nn = grow & (NN - 1);
#pragma unroll
    for (int i = 0; i < 4; i++)
        hT[((size_t)(b * CC + c0 + i)) * NN + nn] = f2bf(acc2[i]);
}

// ---------------------------------------------------------------------------
// rowsum_v2: r[row] = sum_j sigmoid(u[row]+v[j]) * adj[row][j]
// one WAVE per row, 4 rows/block, grid 2048, no block-level sync.
// ---------------------------------------------------------------------------
__global__ __launch_bounds__(256) void rowsum_v2(
    const float* __restrict__ adj, const float* __restrict__ u,
    const float* __restrict__ v, float* __restrict__ r)
{
    const int wave = threadIdx.x >> 6;
    const int lane = threadIdx.x & 63;
    const int row  = blockIdx.x * 4 + wave;
    const int b = row >> 12;
    const float un = u[row];                 // already includes ba
    const floatx4* arow = (const floatx4*)(adj + (size_t)row * NN);
    const floatx4* vb = (const floatx4*)(v + b * NN);

    float p0 = 0.f, p1 = 0.f, p2 = 0.f, p3 = 0.f;
#pragma unroll 4
    for (int i = 0; i < 16; i++) {
        int idx = lane + i * 64;
        floatx4 a4 = arow[idx];
        floatx4 v4 = vb[idx];
        p0 = fmaf(a4.x, sigf(un + v4.x), p0);
        p1 = fmaf(a4.y, sigf(un + v4.y), p1);
        p2 = fmaf(a4.z, sigf(un + v4.z), p2);
        p3 = fmaf(a4.w, sigf(un + v4.w), p3);
    }
    float p = (p0 + p1) + (p2 + p3);
#pragma unroll
    for (int off = 32; off > 0; off >>= 1) p += __shfl_down(p, off);
    if (lane == 0) r[row] = p;
}

// ---------------------------------------------------------------------------
// attn_v2: a = sigmoid(u+v)*adj/r (write fp32), h_out += a @ h (MFMA bf16).
// Block = 16 rows x 1024 j (4 waves x 256 j). Grid = 512 row-tiles x 4 = 2048
// -> 8 blocks/CU, 32 waves/CU. Cross-wave LDS reduce, then atomics (4/elem).
// ---------------------------------------------------------------------------
__global__ __launch_bounds__(256, 8) void attn_v2(
    const float* __restrict__ adj, const float* __restrict__ u,
    const float* __restrict__ v, const float* __restrict__ r,
    const short* __restrict__ hT,
    float* __restrict__ hout, float* __restrict__ aout)
{
    __shared__ float red[4][16][CC + 1];   // 16.6 KB

    const int wave = threadIdx.x >> 6;
    const int lane = threadIdx.x & 63;
    const int quad = lane >> 4;
    const int m16  = lane & 15;

    const int tile = blockIdx.x >> 2;      // 0..511 row-tile
    const int jq   = blockIdx.x & 3;       // j quarter
    const int row0 = tile * 16;
    const int b  = row0 >> 12;
    const int n0 = row0 & (NN - 1);
    const int n  = n0 + m16;

    const size_t rowbase = ((size_t)(b * NN + n)) * NN;
    const float un    = u[b * NN + n];     // includes ba
    const float inv_r = 1.0f / (r[b * NN + n] + 1e-10f);
    const float* vb = v + b * NN;

    floatx4 acc[4];
#pragma unroll
    for (int g = 0; g < 4; g++) acc[g] = (floatx4){0.f, 0.f, 0.f, 0.f};

    const int jbase = jq * 1024 + wave * 256;
#pragma unroll 2
    for (int step = 0; step < 8; step++) {
        const int jb = jbase + step * 32 + quad * 8;
        const float* ap = adj + rowbase + jb;
        floatx4 a0 = *(const floatx4*)ap;
        floatx4 a1 = *(const floatx4*)(ap + 4);
        floatx4 v0 = *(const floatx4*)(vb + jb);
        floatx4 v1 = *(const floatx4*)(vb + jb + 4);

        float av[8] = {a0.x, a0.y, a0.z, a0.w, a1.x, a1.y, a1.z, a1.w};
        float vv[8] = {v0.x, v0.y, v0.z, v0.w, v1.x, v1.y, v1.z, v1.w};

        floatx4 o0, o1;
        short8 af;
#pragma unroll
        for (int i = 0; i < 8; i++) {
            float s = av[i] * sigf(un + vv[i]) * inv_r;
            if (i < 4) o0[i] = s; else o1[i - 4] = s;
            af[i] = f2bf(s);
        }
        *(floatx4*)(aout + rowbase + jb)     = o0;
        *(floatx4*)(aout + rowbase + jb + 4) = o1;

#pragma unroll
        for (int g = 0; g < 4; g++) {
            const short8* bp = (const short8*)(hT + ((size_t)(b * CC + g * 16 + m16)) * NN + jb);
            acc[g] = __builtin_amdgcn_mfma_f32_16x16x32_bf16(af, *bp, acc[g], 0, 0, 0);
        }
    }

    // C/D layout: col(m16)=channel, row(quad*4+i)=adj row. Stage to LDS.
#pragma unroll
    for (int g = 0; g < 4; g++) {
        const int c = g * 16 + m16;
#pragma unroll
        for (int i = 0; i < 4; i++)
            red[wave][quad * 4 + i][c] = acc[g][i];
    }
    __syncthreads();

    // 256 threads x 4 elems cover 16x64; sum 4 waves, one atomic per elem.
#pragma unroll
    for (int e = 0; e < 4; e++) {
        const int idx = threadIdx.x * 4 + e;
        const int rr = idx >> 6;
        const int c  = idx & 63;
        float s = red[0][rr][c] + red[1][rr][c] + red[2][rr][c] + red[3][rr][c];
        atomicAdd(&hout[((size_t)(b * NN + n0 + rr)) * CC + c], s);
    }
}

// ---------------------------------------------------------------------------
extern "C" void kernel_launch(void* const* d_in, const int* in_sizes, int n_in,
                              void* d_out, int out_size, void* d_ws, size_t ws_size,
                              hipStream_t stream) {
    (void)in_sizes; (void)n_in; (void)out_size; (void)ws_size;
    const float* x   = (const float*)d_in[0];
    const float* adj = (const float*)d_in[1];
    const float* W1  = (const float*)d_in[2];
    const float* b1  = (const float*)d_in[3];
    const float* W2  = (const float*)d_in[4];
    const float* b2  = (const float*)d_in[5];
    const float* Wa  = (const float*)d_in[6];
    const float* ba  = (const float*)d_in[7];

    float* hout = (float*)d_out;                       // [B,N,64]
    float* aout = hout + (size_t)BB * NN * CC;         // [B,N,N]

    char* ws = (char*)d_ws;
    short* hT = (short*)ws;                            // bf16 [B][64][N]
    float* u  = (float*)(ws + (size_t)BB * CC * NN * sizeof(short));
    float* vv = u + BB * NN;
    float* r  = vv + BB * NN;

    hipMemsetAsync(d_out, 0, (size_t)BB * NN * CC * sizeof(float), stream);
    feat_v2<<<BB * NN / 16, 256, 0, stream>>>(x, W1, b1, W2, b2, Wa, ba, hT, u, vv);
    rowsum_v2<<<BB * NN / 4, 256, 0, stream>>>(adj, u, vv, r);
    attn_v2<<<(BB * NN / 16) * 4, 256, 0, stream>>>(adj, u, vv, r, hT, hout, aout);
}